// Round 1
// baseline (88.523 us; speedup 1.0000x reference)
//
#include <hip/hip_runtime.h>

// ClassConditionalBatchNorm2d (eval path, alpha=0.5)
// x: [B=128, C=128, H=56, W=56] f32; out same.
// out[b,c,h,w] = (x - mean[b,c]) * rsqrt(var[b,c]+eps) * weight[c] + bias[c]
// mean[b,c] = 0.5*gmean[c] + 0.5*cmean[labels[b],c]   (same for var)
//
// Pure memory-bound elementwise: 411 MB traffic -> ~65 us floor @ 6.3 TB/s.

constexpr int   B_      = 128;
constexpr int   C_      = 128;
constexpr int   HW_     = 56 * 56;      // 3136, divisible by 4
constexpr int   HW4_    = HW_ / 4;      // 784 float4 per plane
constexpr int   NPLANES = B_ * C_;      // 16384
constexpr float EPS_    = 1e-5f;

__global__ __launch_bounds__(256) void ccbn_eval_kernel(
    const float* __restrict__ x,
    const int*   __restrict__ labels,
    const float* __restrict__ weight,
    const float* __restrict__ bias,
    const float* __restrict__ gmean,
    const float* __restrict__ gvar,
    const float* __restrict__ cmean,
    const float* __restrict__ cvar,
    float* __restrict__ out)
{
    for (int plane = blockIdx.x; plane < NPLANES; plane += gridDim.x) {
        const int b = plane >> 7;        // plane / C_
        const int c = plane & (C_ - 1);  // plane % C_

        // All of these are block-uniform -> compiler emits scalar loads;
        // arrays are tiny (<= 64 KB) and L2-resident.
        const int   cls   = labels[b];
        const float mean  = 0.5f * gmean[c] + 0.5f * cmean[cls * C_ + c];
        const float var   = 0.5f * gvar[c]  + 0.5f * cvar[cls * C_ + c];
        const float inv_s = rsqrtf(var + EPS_);
        const float scale = inv_s * weight[c];
        const float shift = bias[c] - mean * scale;

        const float4* __restrict__ xp =
            reinterpret_cast<const float4*>(x + (size_t)plane * HW_);
        float4* __restrict__ op =
            reinterpret_cast<float4*>(out + (size_t)plane * HW_);

        #pragma unroll 1
        for (int j = threadIdx.x; j < HW4_; j += 256) {
            float4 v = xp[j];
            v.x = fmaf(v.x, scale, shift);
            v.y = fmaf(v.y, scale, shift);
            v.z = fmaf(v.z, scale, shift);
            v.w = fmaf(v.w, scale, shift);
            op[j] = v;
        }
    }
}

extern "C" void kernel_launch(void* const* d_in, const int* in_sizes, int n_in,
                              void* d_out, int out_size, void* d_ws, size_t ws_size,
                              hipStream_t stream) {
    const float* x      = (const float*)d_in[0];
    const int*   labels = (const int*)  d_in[1];
    const float* weight = (const float*)d_in[2];
    const float* bias   = (const float*)d_in[3];
    const float* gmean  = (const float*)d_in[4];
    const float* gvar   = (const float*)d_in[5];
    const float* cmean  = (const float*)d_in[6];
    const float* cvar   = (const float*)d_in[7];
    float* out = (float*)d_out;

    // 2048 blocks (~8/CU), grid-stride over the 16384 (b,c) planes.
    dim3 grid(2048), block(256);
    hipLaunchKernelGGL(ccbn_eval_kernel, grid, block, 0, stream,
                       x, labels, weight, bias, gmean, gvar, cmean, cvar, out);
}

// Round 2
// 77.779 us; speedup vs baseline: 1.1381x; 1.1381x over previous
//
#include <hip/hip_runtime.h>

// ClassConditionalBatchNorm2d (eval, alpha=0.5) — round 2
// out[b,c,h,w] = x * scale[b,c] + shift[b,c]
//   scale = rsqrt(0.5*(gvar[c]+cvar[cls,c]) + eps) * weight[c]
//   shift = bias[c] - mean*scale,  mean = 0.5*(gmean[c]+cmean[cls,c])
//
// Structure: 2048 blocks, each owns EXACTLY 8 consecutive (b,c) planes =
// one contiguous 6272-float4 chunk. 8-entry scale/shift LDS table computed
// once per block; flat constant-trip-count streaming loop (no per-plane
// serialization, 2% tail instead of 23%). NT hints: both streams touch-once.

typedef float f4 __attribute__((ext_vector_type(4)));

constexpr int   C_    = 128;
constexpr int   HW4_  = 784;            // 3136/4 float4 per plane
constexpr int   PPB   = 8;              // planes per block
constexpr int   CHUNK = PPB * HW4_;     // 6272 float4 per block
constexpr int   NBLK  = 16384 / PPB;    // 2048 blocks (exact)
constexpr int   FULL_ITERS = CHUNK / 256;  // 24 (6144), tail = 128
constexpr float EPS_  = 1e-5f;

__global__ __launch_bounds__(256) void ccbn_eval_kernel(
    const float* __restrict__ x,
    const int*   __restrict__ labels,
    const float* __restrict__ weight,
    const float* __restrict__ bias,
    const float* __restrict__ gmean,
    const float* __restrict__ gvar,
    const float* __restrict__ cmean,
    const float* __restrict__ cvar,
    float* __restrict__ out)
{
    __shared__ float ssc[PPB];
    __shared__ float ssh[PPB];

    const int t = threadIdx.x;
    if (t < PPB) {
        const int plane = blockIdx.x * PPB + t;   // 8 consecutive planes
        const int b   = plane >> 7;               // /128
        const int c   = plane & (C_ - 1);
        const int cls = labels[b];
        const float mean  = 0.5f * (gmean[c] + cmean[cls * C_ + c]);
        const float var   = 0.5f * (gvar[c]  + cvar[cls * C_ + c]);
        const float scale = rsqrtf(var + EPS_) * weight[c];
        ssc[t] = scale;
        ssh[t] = fmaf(-mean, scale, bias[c]);
    }
    __syncthreads();

    const size_t base = (size_t)blockIdx.x * CHUNK;
    const f4* __restrict__ xp = reinterpret_cast<const f4*>(x) + base;
    f4* __restrict__       op = reinterpret_cast<f4*>(out) + base;

    #pragma unroll 8
    for (int it = 0; it < FULL_ITERS; ++it) {
        const int j  = t + it * 256;
        const int pl = j / HW4_;                  // magic-mul, 0..7
        const float sc = ssc[pl];
        const float sh = ssh[pl];
        f4 v = __builtin_nontemporal_load(xp + j);
        v[0] = fmaf(v[0], sc, sh);
        v[1] = fmaf(v[1], sc, sh);
        v[2] = fmaf(v[2], sc, sh);
        v[3] = fmaf(v[3], sc, sh);
        __builtin_nontemporal_store(v, op + j);
    }
    // tail: elements 6144..6271, all inside plane 7
    if (t < CHUNK - FULL_ITERS * 256) {
        const int j = FULL_ITERS * 256 + t;
        const float sc = ssc[PPB - 1];
        const float sh = ssh[PPB - 1];
        f4 v = __builtin_nontemporal_load(xp + j);
        v[0] = fmaf(v[0], sc, sh);
        v[1] = fmaf(v[1], sc, sh);
        v[2] = fmaf(v[2], sc, sh);
        v[3] = fmaf(v[3], sc, sh);
        __builtin_nontemporal_store(v, op + j);
    }
}

extern "C" void kernel_launch(void* const* d_in, const int* in_sizes, int n_in,
                              void* d_out, int out_size, void* d_ws, size_t ws_size,
                              hipStream_t stream) {
    const float* x      = (const float*)d_in[0];
    const int*   labels = (const int*)  d_in[1];
    const float* weight = (const float*)d_in[2];
    const float* bias   = (const float*)d_in[3];
    const float* gmean  = (const float*)d_in[4];
    const float* gvar   = (const float*)d_in[5];
    const float* cmean  = (const float*)d_in[6];
    const float* cvar   = (const float*)d_in[7];
    float* out = (float*)d_out;

    hipLaunchKernelGGL(ccbn_eval_kernel, dim3(NBLK), dim3(256), 0, stream,
                       x, labels, weight, bias, gmean, gvar, cmean, cvar, out);
}